// Round 1
// baseline (1571.682 us; speedup 1.0000x reference)
//
#include <hip/hip_runtime.h>
#include <hip/hip_bf16.h>
#include <math.h>

// Shapes: B=1, N=64, L=256, nf=64, npj=32, nfo=128
// Layouts (all fp32):
//   msa        [64][256][64]
//   pair_orig  [256][256][128]   (pix = i*256+l, channel-last)
//   xd         [64][256][32]
//   feat       [256][128]
//   intermediates: [pix=65536][128] channel-last

__device__ __forceinline__ float eluf(float x) { return x > 0.f ? x : expm1f(x); }

// ---------------------------------------------------------------- x_down
__global__ __launch_bounds__(256) void k_xdown(
    const float* __restrict__ msa, const float* __restrict__ W1,
    const float* __restrict__ b1, float* __restrict__ xd)
{
    __shared__ float w1s[32 * 65];
    const int tid = threadIdx.x;
    for (int t = tid; t < 2048; t += 256) w1s[(t >> 6) * 65 + (t & 63)] = W1[t];
    __syncthreads();
    const int id = blockIdx.x * 256 + tid;
    const int p = id & 31, l = (id >> 5) & 255, n = id >> 13;
    const float* mrow = msa + (((n << 8) + l) << 6);
    const float* wrow = w1s + p * 65;
    float s = 0.f;
#pragma unroll 8
    for (int f = 0; f < 64; ++f) s += mrow[f] * wrow[f];
    xd[id] = s + b1[p];
}

// ---------------------------------------------------------------- feat_1d
__global__ __launch_bounds__(256) void k_feat(
    const float* __restrict__ msa, float* __restrict__ feat)
{
    const int id = blockIdx.x * 256 + threadIdx.x;   // 32768
    const int c = id & 127, l = id >> 7;
    float v;
    if (c < 64) {
        float s = 0.f;
        for (int n = 0; n < 64; ++n) s += msa[(((n << 8) + l) << 6) + c];
        v = s * (1.f / 64.f);
    } else {
        v = msa[(l << 6) + (c - 64)];
    }
    feat[id] = v;
}

// ------------------------------------------- G2T = (g_ln*W2)^T, S1, S2
__global__ __launch_bounds__(256) void k_g2(
    const float* __restrict__ W2, const float* __restrict__ g_ln,
    const float* __restrict__ be_ln, const float* __restrict__ b2,
    float* __restrict__ G2T, float* __restrict__ S1, float* __restrict__ S2)
{
    const int o = blockIdx.x, tid = threadIdx.x;
    float s1 = 0.f, s2 = 0.f;
    for (int c = tid; c < 1024; c += 256) {
        float w = W2[o * 1024 + c];
        float gw = g_ln[c] * w;
        G2T[c * 128 + o] = gw;
        s1 += gw;
        s2 += be_ln[c] * w;
    }
#pragma unroll
    for (int off = 32; off; off >>= 1) { s1 += __shfl_down(s1, off); s2 += __shfl_down(s2, off); }
    __shared__ float r1[4], r2[4];
    if ((tid & 63) == 0) { r1[tid >> 6] = s1; r2[tid >> 6] = s2; }
    __syncthreads();
    if (tid == 0) {
        S1[o] = r1[0] + r1[1] + r1[2] + r1[3];
        S2[o] = r2[0] + r2[1] + r2[2] + r2[3] + b2[o];
    }
}

// ------------------------------------------- WcT[c][o] = Wc0[o][c], c<256
__global__ __launch_bounds__(256) void k_wct(
    const float* __restrict__ Wc0, float* __restrict__ WcT)
{
    const int t = blockIdx.x * 256 + threadIdx.x;   // 32768
    const int c = t >> 7, o = t & 127;
    WcT[c * 128 + o] = Wc0[o * 512 + c];
}

// ------------------------------------------- Ai/Bl from feat & Wc0 tails
__global__ __launch_bounds__(128) void k_ab(
    const float* __restrict__ feat, const float* __restrict__ Wc0,
    float* __restrict__ Ai, float* __restrict__ Bl)
{
    __shared__ float fs[128];
    const int r = blockIdx.x, o = threadIdx.x;
    fs[o] = feat[r * 128 + o];
    __syncthreads();
    const float* wa = Wc0 + o * 512 + 256;
    const float* wb = Wc0 + o * 512 + 384;
    float a = 0.f, b = 0.f;
#pragma unroll 4
    for (int c = 0; c < 128; ++c) { float f = fs[c]; a += f * wa[c]; b += f * wb[c]; }
    Ai[r * 128 + o] = a;
    Bl[r * 128 + o] = b;
}

// ------------- fused outer-product-mean + LayerNorm + W2 projection
// grid (16, 256): blockIdx.y = i, blockIdx.x*16 = l0. 256 threads.
__global__ __launch_bounds__(256) void k_pair(
    const float* __restrict__ xd, const float* __restrict__ G2T,
    const float* __restrict__ S1, const float* __restrict__ S2,
    float* __restrict__ pair2)
{
    __shared__ float xi_s[2048];
    __shared__ float xl_s[2048];
    __shared__ float P_st[16 * 66];
    __shared__ float g2_s[64 * 132];
    __shared__ float red_s[4][16], red_q[4][16];
    __shared__ float mus[16], rstds[16];

    const int tid = threadIdx.x;
    const int i = blockIdx.y;
    const int l0 = blockIdx.x << 4;
    const int lane = tid & 63, wid = tid >> 6;

    for (int t = tid; t < 2048; t += 256)
        xi_s[t] = xd[(((t >> 5) << 8) + i) * 32 + (t & 31)];

    const int pp = tid >> 3;            // p index of this thread's 4 c's
    const int q0 = (tid << 2) & 31;     // q base (4-aligned)

    float Preg[16][4];
#pragma unroll
    for (int pos = 0; pos < 16; ++pos) {
        __syncthreads();
        for (int t = tid; t < 2048; t += 256)
            xl_s[t] = xd[(((t >> 5) << 8) + l0 + pos) * 32 + (t & 31)];
        __syncthreads();
        float a0 = 0.f, a1 = 0.f, a2 = 0.f, a3 = 0.f;
#pragma unroll 8
        for (int n = 0; n < 64; ++n) {
            const float xa = xi_s[(n << 5) + pp];
            const float4 xb = *(const float4*)&xl_s[(n << 5) + q0];
            a0 += xa * xb.x; a1 += xa * xb.y; a2 += xa * xb.z; a3 += xa * xb.w;
        }
        Preg[pos][0] = a0 * 0.015625f; Preg[pos][1] = a1 * 0.015625f;
        Preg[pos][2] = a2 * 0.015625f; Preg[pos][3] = a3 * 0.015625f;
    }

    // per-position LayerNorm stats over 1024 entries
#pragma unroll
    for (int pos = 0; pos < 16; ++pos) {
        float s = Preg[pos][0] + Preg[pos][1] + Preg[pos][2] + Preg[pos][3];
        float q = Preg[pos][0] * Preg[pos][0] + Preg[pos][1] * Preg[pos][1]
                + Preg[pos][2] * Preg[pos][2] + Preg[pos][3] * Preg[pos][3];
#pragma unroll
        for (int off = 32; off; off >>= 1) { s += __shfl_down(s, off); q += __shfl_down(q, off); }
        if (lane == 0) { red_s[wid][pos] = s; red_q[wid][pos] = q; }
    }
    __syncthreads();
    if (tid < 16) {
        float s = red_s[0][tid] + red_s[1][tid] + red_s[2][tid] + red_s[3][tid];
        float q = red_q[0][tid] + red_q[1][tid] + red_q[2][tid] + red_q[3][tid];
        float mu = s * (1.f / 1024.f);
        float var = q * (1.f / 1024.f) - mu * mu;
        mus[tid] = mu;
        rstds[tid] = rsqrtf(var + 1e-5f);
    }

    // projection: out[pos][o] = sum_c P[pos][c] * G2[o][c]
    const int og = tid & 31, pg = tid >> 5;
    const int o0 = og << 2;
    float acc0[4] = {0.f, 0.f, 0.f, 0.f}, acc1[4] = {0.f, 0.f, 0.f, 0.f};
    for (int k = 0; k < 16; ++k) {
        __syncthreads();
        if ((tid >> 4) == k) {
            const int tt = tid & 15;
#pragma unroll
            for (int pos = 0; pos < 16; ++pos) {
                P_st[pos * 66 + (tt << 2) + 0] = Preg[pos][0];
                P_st[pos * 66 + (tt << 2) + 1] = Preg[pos][1];
                P_st[pos * 66 + (tt << 2) + 2] = Preg[pos][2];
                P_st[pos * 66 + (tt << 2) + 3] = Preg[pos][3];
            }
        }
        for (int t = tid; t < 8192; t += 256) {
            const int o = t & 127, cl = t >> 7;
            g2_s[cl * 132 + o] = G2T[(((k << 6) + cl) << 7) + o];
        }
        __syncthreads();
#pragma unroll 4
        for (int cl = 0; cl < 64; ++cl) {
            const float4 g4 = *(const float4*)&g2_s[cl * 132 + o0];
            const float p0 = P_st[(pg << 1) * 66 + cl];
            const float p1 = P_st[((pg << 1) + 1) * 66 + cl];
            acc0[0] += p0 * g4.x; acc0[1] += p0 * g4.y; acc0[2] += p0 * g4.z; acc0[3] += p0 * g4.w;
            acc1[0] += p1 * g4.x; acc1[1] += p1 * g4.y; acc1[2] += p1 * g4.z; acc1[3] += p1 * g4.w;
        }
    }
    const float4 s1v = *(const float4*)&S1[o0];
    const float4 s2v = *(const float4*)&S2[o0];
    const int posA = pg << 1;
    {
        const float mu = mus[posA], rs = rstds[posA];
        float4 r;
        r.x = rs * (acc0[0] - mu * s1v.x) + s2v.x;
        r.y = rs * (acc0[1] - mu * s1v.y) + s2v.y;
        r.z = rs * (acc0[2] - mu * s1v.z) + s2v.z;
        r.w = rs * (acc0[3] - mu * s1v.w) + s2v.w;
        *(float4*)&pair2[((i << 8) + l0 + posA) * 128 + o0] = r;
    }
    {
        const float mu = mus[posA + 1], rs = rstds[posA + 1];
        float4 r;
        r.x = rs * (acc1[0] - mu * s1v.x) + s2v.x;
        r.y = rs * (acc1[1] - mu * s1v.y) + s2v.y;
        r.z = rs * (acc1[2] - mu * s1v.z) + s2v.z;
        r.w = rs * (acc1[3] - mu * s1v.w) + s2v.w;
        *(float4*)&pair2[((i << 8) + l0 + posA + 1) * 128 + o0] = r;
    }
}

// ------------- 1x1 conv over concat(pair_orig, pair2) + Ai + Bl, + stats
// grid 4096 (16 px/block), 256 threads: og = tid&31 (o0=og*4), pg = tid>>5 (2 px)
__global__ __launch_bounds__(256) void k_conv1x1(
    const float* __restrict__ pairo, const float* __restrict__ pair2,
    const float* __restrict__ Ai, const float* __restrict__ Bl,
    const float* __restrict__ WcT, float* __restrict__ X0,
    float* __restrict__ ps, float* __restrict__ pq)
{
    __shared__ float cat_s[16 * 260];
    __shared__ float w_s[32 * 132];
    __shared__ float red_s[4][32][4], red_q[4][32][4];
    const int tid = threadIdx.x;
    const int pix0 = blockIdx.x << 4;
    for (int t = tid; t < 2048; t += 256) {
        const int px = t >> 7, c = t & 127;
        cat_s[px * 260 + c]       = pairo[(pix0 + px) * 128 + c];
        cat_s[px * 260 + 128 + c] = pair2[(pix0 + px) * 128 + c];
    }
    const int og = tid & 31, pg = tid >> 5;
    const int o0 = og << 2;
    float acc0[4] = {0.f, 0.f, 0.f, 0.f}, acc1[4] = {0.f, 0.f, 0.f, 0.f};
    for (int ch = 0; ch < 8; ++ch) {
        __syncthreads();
        for (int t = tid; t < 4096; t += 256) {
            const int o = t & 127, cc = t >> 7;
            w_s[cc * 132 + o] = WcT[(((ch << 5) + cc) << 7) + o];
        }
        __syncthreads();
        const int cb = ch << 5;
#pragma unroll 4
        for (int cc = 0; cc < 32; ++cc) {
            const float4 w4 = *(const float4*)&w_s[cc * 132 + o0];
            const float p0v = cat_s[(pg << 1) * 260 + cb + cc];
            const float p1v = cat_s[((pg << 1) + 1) * 260 + cb + cc];
            acc0[0] += p0v * w4.x; acc0[1] += p0v * w4.y; acc0[2] += p0v * w4.z; acc0[3] += p0v * w4.w;
            acc1[0] += p1v * w4.x; acc1[1] += p1v * w4.y; acc1[2] += p1v * w4.z; acc1[3] += p1v * w4.w;
        }
    }
    float v0[4], v1[4];
    {
        const int pix = pix0 + (pg << 1);
        const int ii = pix >> 8, ll = pix & 255;
        const float4 a4 = *(const float4*)&Ai[ii * 128 + o0];
        const float4 b4 = *(const float4*)&Bl[ll * 128 + o0];
        v0[0] = acc0[0] + a4.x + b4.x; v0[1] = acc0[1] + a4.y + b4.y;
        v0[2] = acc0[2] + a4.z + b4.z; v0[3] = acc0[3] + a4.w + b4.w;
        *(float4*)&X0[pix * 128 + o0] = make_float4(v0[0], v0[1], v0[2], v0[3]);
    }
    {
        const int pix = pix0 + (pg << 1) + 1;
        const int ii = pix >> 8, ll = pix & 255;
        const float4 a4 = *(const float4*)&Ai[ii * 128 + o0];
        const float4 b4 = *(const float4*)&Bl[ll * 128 + o0];
        v1[0] = acc1[0] + a4.x + b4.x; v1[1] = acc1[1] + a4.y + b4.y;
        v1[2] = acc1[2] + a4.z + b4.z; v1[3] = acc1[3] + a4.w + b4.w;
        *(float4*)&X0[pix * 128 + o0] = make_float4(v1[0], v1[1], v1[2], v1[3]);
    }
    float lsum[4], lsq[4];
#pragma unroll
    for (int b = 0; b < 4; ++b) {
        lsum[b] = v0[b] + v1[b];
        lsq[b] = v0[b] * v0[b] + v1[b] * v1[b];
    }
    const int wid = tid >> 6;
#pragma unroll
    for (int b = 0; b < 4; ++b) {
        lsum[b] += __shfl_xor(lsum[b], 32);
        lsq[b]  += __shfl_xor(lsq[b], 32);
    }
    if ((tid & 63) < 32) {
#pragma unroll
        for (int b = 0; b < 4; ++b) { red_s[wid][og][b] = lsum[b]; red_q[wid][og][b] = lsq[b]; }
    }
    __syncthreads();
    if (tid < 128) {
        const int o = tid, ogg = o >> 2, b = o & 3;
        const float s = red_s[0][ogg][b] + red_s[1][ogg][b] + red_s[2][ogg][b] + red_s[3][ogg][b];
        const float q = red_q[0][ogg][b] + red_q[1][ogg][b] + red_q[2][ogg][b] + red_q[3][ogg][b];
        ps[blockIdx.x * 128 + o] = s;
        pq[blockIdx.x * 128 + o] = q;
    }
}

// ------------------------------------------- per-channel IN params
__global__ __launch_bounds__(256) void k_stats(
    const float* __restrict__ ps, const float* __restrict__ pq, int R,
    const float* __restrict__ g, const float* __restrict__ be,
    float* __restrict__ scl, float* __restrict__ sft)
{
    const int o = blockIdx.x, tid = threadIdx.x;
    float s = 0.f, q = 0.f;
    for (int r = tid; r < R; r += 256) { s += ps[r * 128 + o]; q += pq[r * 128 + o]; }
#pragma unroll
    for (int off = 32; off; off >>= 1) { s += __shfl_down(s, off); q += __shfl_down(q, off); }
    __shared__ float rs[4], rq[4];
    if ((tid & 63) == 0) { rs[tid >> 6] = s; rq[tid >> 6] = q; }
    __syncthreads();
    if (tid == 0) {
        s = rs[0] + rs[1] + rs[2] + rs[3];
        q = rq[0] + rq[1] + rq[2] + rq[3];
        const float mean = s * (1.f / 65536.f);
        const float var = q * (1.f / 65536.f) - mean * mean;
        const float rstd = rsqrtf(var + 1e-6f);
        const float sc = g[o] * rstd;
        scl[o] = sc;
        sft[o] = be[o] - mean * sc;
    }
}

// ------------------------------------------- elementwise norm + ELU
__global__ __launch_bounds__(256) void k_norm_elu(
    const float* in, float* out,
    const float* __restrict__ scl, const float* __restrict__ sft)
{
    const int total = 2097152;
    for (int i = blockIdx.x * 256 + threadIdx.x; i < total; i += gridDim.x * 256) {
        const float4 v = ((const float4*)in)[i];
        const int o0 = (i & 31) << 2;
        const float4 sc = *(const float4*)&scl[o0];
        const float4 sh = *(const float4*)&sft[o0];
        float4 r;
        r.x = eluf(v.x * sc.x + sh.x);
        r.y = eluf(v.y * sc.y + sh.y);
        r.z = eluf(v.z * sc.z + sh.z);
        r.w = eluf(v.w * sc.w + sh.w);
        ((float4*)out)[i] = r;
    }
}

// ------------------------------------------- weight transpose [o][ic][ky][kx] -> [tap][ic][o]
__global__ __launch_bounds__(256) void k_wtrans(
    const float* __restrict__ src, float* __restrict__ dst)
{
    const int t = blockIdx.x * 256 + threadIdx.x;   // 147456
    const int kx = t % 3;
    const int t2 = t / 3;
    const int ky = t2 % 3;
    const int t3 = t2 / 3;
    const int ic = t3 & 127;
    const int o = t3 >> 7;
    dst[(((ky * 3 + kx) << 7) + ic) * 128 + o] = src[t];
}

// ------------------------------------------- 3x3 conv + block stats
// grid (4, 256): 64 px of row y per block. 256 thr: og=tid&15, pg=tid>>4 (4 px)
__global__ __launch_bounds__(256) void k_conv3x3(
    const float* __restrict__ in, const float* __restrict__ wgtT,
    float* __restrict__ out, float* __restrict__ ps, float* __restrict__ pq)
{
    __shared__ float in_s[3 * 66 * 9];
    __shared__ float w_s[72 * 132];
    __shared__ float red_s[4][16][8], red_q[4][16][8];
    const int tid = threadIdx.x;
    const int x0 = blockIdx.x << 6;
    const int y = blockIdx.y;
    const int og = tid & 15, pg = tid >> 4;
    const int px0 = pg << 2;
    float acc[4][8];
#pragma unroll
    for (int a = 0; a < 4; ++a)
#pragma unroll
        for (int b = 0; b < 8; ++b) acc[a][b] = 0.f;

    for (int icc = 0; icc < 16; ++icc) {
        __syncthreads();
        for (int t = tid; t < 1584; t += 256) {
            const int ic = t & 7, cr = t >> 3;
            const int xl = cr % 66, ky = cr / 66;
            const int yy = y + ky - 1, xx = x0 + xl - 1;
            float v = 0.f;
            if ((unsigned)yy < 256u && (unsigned)xx < 256u)
                v = in[(((yy << 8) + xx) << 7) + (icc << 3) + ic];
            in_s[(ky * 66 + xl) * 9 + ic] = v;
        }
        for (int t = tid; t < 9216; t += 256) {
            const int o = t & 127, r = t >> 7;
            const int tap = r >> 3, icl = r & 7;
            w_s[r * 132 + o] = wgtT[(((tap << 7) + (icc << 3) + icl) << 7) + o];
        }
        __syncthreads();
#pragma unroll 1
        for (int tap = 0; tap < 9; ++tap) {
            const int ky = tap / 3, kx = tap % 3;
            const int ibase = (ky * 66 + px0 + kx) * 9;
#pragma unroll
            for (int icl = 0; icl < 8; ++icl) {
                const int r = (tap << 3) + icl;
                const float4 wlo = *(const float4*)&w_s[r * 132 + (og << 2)];
                const float4 whi = *(const float4*)&w_s[r * 132 + 64 + (og << 2)];
#pragma unroll
                for (int p = 0; p < 4; ++p) {
                    const float iv = in_s[ibase + p * 9 + icl];
                    acc[p][0] += iv * wlo.x; acc[p][1] += iv * wlo.y;
                    acc[p][2] += iv * wlo.z; acc[p][3] += iv * wlo.w;
                    acc[p][4] += iv * whi.x; acc[p][5] += iv * whi.y;
                    acc[p][6] += iv * whi.z; acc[p][7] += iv * whi.w;
                }
            }
        }
    }
    float lsum[8], lsq[8];
#pragma unroll
    for (int b = 0; b < 8; ++b) { lsum[b] = 0.f; lsq[b] = 0.f; }
#pragma unroll
    for (int p = 0; p < 4; ++p) {
        const int xx = x0 + px0 + p;
        const int base = (((y << 8) + xx) << 7);
        *(float4*)&out[base + (og << 2)] = make_float4(acc[p][0], acc[p][1], acc[p][2], acc[p][3]);
        *(float4*)&out[base + 64 + (og << 2)] = make_float4(acc[p][4], acc[p][5], acc[p][6], acc[p][7]);
#pragma unroll
        for (int b = 0; b < 8; ++b) { const float v = acc[p][b]; lsum[b] += v; lsq[b] += v * v; }
    }
#pragma unroll
    for (int b = 0; b < 8; ++b) {
        lsum[b] += __shfl_xor(lsum[b], 16); lsum[b] += __shfl_xor(lsum[b], 32);
        lsq[b]  += __shfl_xor(lsq[b], 16);  lsq[b]  += __shfl_xor(lsq[b], 32);
    }
    const int wid = tid >> 6;
    if ((tid & 63) < 16) {
#pragma unroll
        for (int b = 0; b < 8; ++b) { red_s[wid][og][b] = lsum[b]; red_q[wid][og][b] = lsq[b]; }
    }
    __syncthreads();
    if (tid < 128) {
        const int o = tid;
        int ogg, b;
        if (o < 64) { ogg = o >> 2; b = o & 3; } else { ogg = (o - 64) >> 2; b = 4 + ((o - 64) & 3); }
        const float s = red_s[0][ogg][b] + red_s[1][ogg][b] + red_s[2][ogg][b] + red_s[3][ogg][b];
        const float q = red_q[0][ogg][b] + red_q[1][ogg][b] + red_q[2][ogg][b] + red_q[3][ogg][b];
        const int blk = (y << 2) + blockIdx.x;
        ps[blk * 128 + o] = s;
        pq[blk * 128 + o] = q;
    }
}

// ------------------------------------------- final: out = elu(x1 + norm(h2))
__global__ __launch_bounds__(256) void k_final(
    const float* x1, const float* __restrict__ h,
    const float* __restrict__ scl, const float* __restrict__ sft,
    float* outp)
{
    const int total = 2097152;
    for (int i = blockIdx.x * 256 + threadIdx.x; i < total; i += gridDim.x * 256) {
        const float4 a = ((const float4*)x1)[i];
        const float4 hv = ((const float4*)h)[i];
        const int o0 = (i & 31) << 2;
        const float4 sc = *(const float4*)&scl[o0];
        const float4 sh = *(const float4*)&sft[o0];
        float4 r;
        r.x = eluf(a.x + hv.x * sc.x + sh.x);
        r.y = eluf(a.y + hv.y * sc.y + sh.y);
        r.z = eluf(a.z + hv.z * sc.z + sh.z);
        r.w = eluf(a.w + hv.w * sc.w + sh.w);
        ((float4*)outp)[i] = r;
    }
}

extern "C" void kernel_launch(void* const* d_in, const int* in_sizes, int n_in,
                              void* d_out, int out_size, void* d_ws, size_t ws_size,
                              hipStream_t stream)
{
    const float* msa   = (const float*)d_in[0];
    const float* pairo = (const float*)d_in[1];
    const float* W1    = (const float*)d_in[2];
    const float* b1    = (const float*)d_in[3];
    const float* g_ln  = (const float*)d_in[4];
    const float* be_ln = (const float*)d_in[5];
    const float* W2    = (const float*)d_in[6];
    const float* b2    = (const float*)d_in[7];
    const float* Wc0   = (const float*)d_in[8];
    const float* g0    = (const float*)d_in[9];
    const float* be0   = (const float*)d_in[10];
    const float* Wr1   = (const float*)d_in[11];
    const float* g1    = (const float*)d_in[12];
    const float* be1   = (const float*)d_in[13];
    const float* Wr2   = (const float*)d_in[14];
    const float* g2    = (const float*)d_in[15];
    const float* be2   = (const float*)d_in[16];

    float* ws    = (float*)d_ws;
    float* xd    = ws;                    // 524288
    float* feat  = ws + 524288;           // 32768
    float* Ai    = ws + 557056;           // 32768
    float* Bl    = ws + 589824;           // 32768
    float* G2T   = ws + 622592;           // 131072
    float* S1    = ws + 753664;           // 128
    float* S2    = ws + 753792;           // 128
    float* scl   = ws + 753920;           // 128
    float* sft   = ws + 754048;           // 128
    float* WcT   = ws + 754176;           // 32768
    float* ps    = ws + 786944;           // 524288
    float* pq    = ws + 1311232;          // 524288
    float* wgtT  = ws + 1835520;          // 147456
    float* pair2 = ws + 1982976;          // 8388608
    float* X0    = ws + 10371584;         // 8388608
    float* X1    = (float*)d_out;         // reuse output as x1 storage

    k_xdown<<<dim3(2048), dim3(256), 0, stream>>>(msa, W1, b1, xd);
    k_feat<<<dim3(128), dim3(256), 0, stream>>>(msa, feat);
    k_g2<<<dim3(128), dim3(256), 0, stream>>>(W2, g_ln, be_ln, b2, G2T, S1, S2);
    k_wct<<<dim3(128), dim3(256), 0, stream>>>(Wc0, WcT);
    k_ab<<<dim3(256), dim3(128), 0, stream>>>(feat, Wc0, Ai, Bl);

    k_pair<<<dim3(16, 256), dim3(256), 0, stream>>>(xd, G2T, S1, S2, pair2);

    k_conv1x1<<<dim3(4096), dim3(256), 0, stream>>>(pairo, pair2, Ai, Bl, WcT, X0, ps, pq);
    k_stats<<<dim3(128), dim3(256), 0, stream>>>(ps, pq, 4096, g0, be0, scl, sft);
    k_norm_elu<<<dim3(4096), dim3(256), 0, stream>>>(X0, X1, scl, sft);

    k_wtrans<<<dim3(576), dim3(256), 0, stream>>>(Wr1, wgtT);
    k_conv3x3<<<dim3(4, 256), dim3(256), 0, stream>>>(X1, wgtT, X0, ps, pq);
    k_stats<<<dim3(128), dim3(256), 0, stream>>>(ps, pq, 1024, g1, be1, scl, sft);
    k_norm_elu<<<dim3(4096), dim3(256), 0, stream>>>(X0, X0, scl, sft);

    k_wtrans<<<dim3(576), dim3(256), 0, stream>>>(Wr2, wgtT);
    k_conv3x3<<<dim3(4, 256), dim3(256), 0, stream>>>(X0, wgtT, pair2, ps, pq);
    k_stats<<<dim3(128), dim3(256), 0, stream>>>(ps, pq, 1024, g2, be2, scl, sft);

    k_final<<<dim3(4096), dim3(256), 0, stream>>>(X1, pair2, scl, sft, (float*)d_out);
}

// Round 2
// 1019.922 us; speedup vs baseline: 1.5410x; 1.5410x over previous
//
#include <hip/hip_runtime.h>
#include <hip/hip_bf16.h>
#include <math.h>

// Shapes: B=1, N=64, L=256, nf=64, npj=32, nfo=128
// pair path: bf16 MFMA GEMMs.
//   xdT   [pos*32+p][n]   bf16  (pos in [0,256), p in [0,32), n in [0,64))
//   P     computed per 64-i chunk: Pc[(i_loc*256+l)*1024 + p*32+q]  bf16
//   G2swz pre-swizzled B-fragments for 16x16x32 mfma
// LN folded into projection epilogue: out = rstd*(P.G2 - mu*S1) + S2

typedef __attribute__((ext_vector_type(8))) short bf16x8;
typedef __attribute__((ext_vector_type(4))) float f32x4;

__device__ __forceinline__ float eluf(float x) { return x > 0.f ? x : expm1f(x); }

// ---------------------------------------------------------------- x_down -> xdT bf16
__global__ __launch_bounds__(256) void k_xdown(
    const float* __restrict__ msa, const float* __restrict__ W1,
    const float* __restrict__ b1, ushort* __restrict__ xdT)
{
    __shared__ float w1s[32 * 65];
    const int tid = threadIdx.x;
    for (int t = tid; t < 2048; t += 256) w1s[(t >> 6) * 65 + (t & 63)] = W1[t];
    __syncthreads();
    const int id = blockIdx.x * 256 + tid;
    const int p = id & 31, l = (id >> 5) & 255, n = id >> 13;
    const float* mrow = msa + (((n << 8) + l) << 6);
    const float* wrow = w1s + p * 65;
    float s = 0.f;
#pragma unroll 8
    for (int f = 0; f < 64; ++f) s += mrow[f] * wrow[f];
    ((__hip_bfloat16*)xdT)[(((l << 5) + p) << 6) + n] = __float2bfloat16(s + b1[p]);
}

// ---------------------------------------------------------------- feat_1d
__global__ __launch_bounds__(256) void k_feat(
    const float* __restrict__ msa, float* __restrict__ feat)
{
    const int id = blockIdx.x * 256 + threadIdx.x;   // 32768
    const int c = id & 127, l = id >> 7;
    float v;
    if (c < 64) {
        float s = 0.f;
        for (int n = 0; n < 64; ++n) s += msa[(((n << 8) + l) << 6) + c];
        v = s * (1.f / 64.f);
    } else {
        v = msa[(l << 6) + (c - 64)];
    }
    feat[id] = v;
}

// ------------------------------------------- S1[o]=sum_c g*W2, S2[o]=sum_c be*W2 + b2
__global__ __launch_bounds__(256) void k_g2(
    const float* __restrict__ W2, const float* __restrict__ g_ln,
    const float* __restrict__ be_ln, const float* __restrict__ b2,
    float* __restrict__ S1, float* __restrict__ S2)
{
    const int o = blockIdx.x, tid = threadIdx.x;
    float s1 = 0.f, s2 = 0.f;
    for (int c = tid; c < 1024; c += 256) {
        float w = W2[o * 1024 + c];
        s1 += g_ln[c] * w;
        s2 += be_ln[c] * w;
    }
#pragma unroll
    for (int off = 32; off; off >>= 1) { s1 += __shfl_down(s1, off); s2 += __shfl_down(s2, off); }
    __shared__ float r1[4], r2[4];
    if ((tid & 63) == 0) { r1[tid >> 6] = s1; r2[tid >> 6] = s2; }
    __syncthreads();
    if (tid == 0) {
        S1[o] = r1[0] + r1[1] + r1[2] + r1[3];
        S2[o] = r2[0] + r2[1] + r2[2] + r2[3] + b2[o];
    }
}

// ------------------------------------------- G2 in B-fragment-swizzled bf16 layout
// G2swz[((kt*8 + nt)*64 + lane)*8 + j] = g_ln[k]*W2[o][k], k = kt*32+(lane>>4)*8+j, o = nt*16+(lane&15)
__global__ __launch_bounds__(256) void k_g2swz(
    const float* __restrict__ W2, const float* __restrict__ g_ln,
    ushort* __restrict__ G2swz)
{
    const int idx = blockIdx.x * 256 + threadIdx.x;   // 131072
    const int j = idx & 7, lane = (idx >> 3) & 63, nt = (idx >> 9) & 7, kt = idx >> 12;
    const int k = kt * 32 + (lane >> 4) * 8 + j;
    const int o = nt * 16 + (lane & 15);
    ((__hip_bfloat16*)G2swz)[idx] = __float2bfloat16(g_ln[k] * W2[o * 1024 + k]);
}

// ------------------------------------------- WcT[c][o] = Wc0[o][c], c<256
__global__ __launch_bounds__(256) void k_wct(
    const float* __restrict__ Wc0, float* __restrict__ WcT)
{
    const int t = blockIdx.x * 256 + threadIdx.x;   // 32768
    const int c = t >> 7, o = t & 127;
    WcT[c * 128 + o] = Wc0[o * 512 + c];
}

// ------------------------------------------- Ai/Bl from feat & Wc0 tails
__global__ __launch_bounds__(128) void k_ab(
    const float* __restrict__ feat, const float* __restrict__ Wc0,
    float* __restrict__ Ai, float* __restrict__ Bl)
{
    __shared__ float fs[128];
    const int r = blockIdx.x, o = threadIdx.x;
    fs[o] = feat[r * 128 + o];
    __syncthreads();
    const float* wa = Wc0 + o * 512 + 256;
    const float* wb = Wc0 + o * 512 + 384;
    float a = 0.f, b = 0.f;
#pragma unroll 4
    for (int c = 0; c < 128; ++c) { float f = fs[c]; a += f * wa[c]; b += f * wb[c]; }
    Ai[r * 128 + o] = a;
    Bl[r * 128 + o] = b;
}

// ------------- outer-product GEMM: P[(i,p),(l,q)] = sum_n xdT[(i,p)][n]*xdT[(l,q)][n] / 64
// grid (64, 16): x = col-block (128 of 8192 (l,q)), y = row-block (128 of 2048 chunk rows)
// 256 thr = 4 waves, wave quadrant 64x64. Also emits per-(i,l) mu/rstd (LN over 1024 pq).
__global__ __launch_bounds__(256) void k_outer(
    const ushort* __restrict__ xdT, ushort* __restrict__ Pc,
    float* __restrict__ muArr, float* __restrict__ rstdArr, int ib)
{
    const int tid = threadIdx.x;
    const int w = tid >> 6, lane = tid & 63;
    const int m_w = (w >> 1) << 6;
    const int n_w = (w & 1) << 6;
    const int lo = lane & 15, kg = lane >> 4;
    const int rowA0 = (ib << 5) + (blockIdx.y << 7) + m_w;
    const int rowB0 = (blockIdx.x << 7) + n_w;

    f32x4 acc[4][4] = {};
#pragma unroll
    for (int ks = 0; ks < 2; ++ks) {
        bf16x8 a[4], b[4];
#pragma unroll
        for (int mt = 0; mt < 4; ++mt)
            a[mt] = *(const bf16x8*)&xdT[(rowA0 + mt * 16 + lo) * 64 + ks * 32 + kg * 8];
#pragma unroll
        for (int nt = 0; nt < 4; ++nt)
            b[nt] = *(const bf16x8*)&xdT[(rowB0 + nt * 16 + lo) * 64 + ks * 32 + kg * 8];
#pragma unroll
        for (int mt = 0; mt < 4; ++mt)
#pragma unroll
            for (int nt = 0; nt < 4; ++nt)
                acc[mt][nt] = __builtin_amdgcn_mfma_f32_16x16x32_bf16(a[mt], b[nt], acc[mt][nt], 0, 0, 0);
    }

    const float sc = 1.f / 64.f;
    // per-(i,l) LayerNorm stats: each 32x32 pq block lives in one wave (2x2 fragments)
#pragma unroll
    for (int ii = 0; ii < 2; ++ii) {
#pragma unroll
        for (int ll = 0; ll < 2; ++ll) {
            float s = 0.f, q = 0.f;
#pragma unroll
            for (int dm = 0; dm < 2; ++dm)
#pragma unroll
                for (int dn = 0; dn < 2; ++dn)
#pragma unroll
                    for (int r = 0; r < 4; ++r) {
                        const float v = acc[ii * 2 + dm][ll * 2 + dn][r] * sc;
                        s += v; q += v * v;
                    }
#pragma unroll
            for (int off = 1; off < 64; off <<= 1) { s += __shfl_xor(s, off); q += __shfl_xor(q, off); }
            if (lane == 0) {
                const int i_loc = (((blockIdx.y << 7) + m_w) >> 5) + ii;
                const int l = (((blockIdx.x << 7) + n_w) >> 5) + ll;
                const int pixg = ((ib + i_loc) << 8) + l;
                const float mu = s * (1.f / 1024.f);
                const float var = q * (1.f / 1024.f) - mu * mu;
                muArr[pixg] = mu;
                rstdArr[pixg] = rsqrtf(var + 1e-5f);
            }
        }
    }
    // store P tile bf16: Pc[(i_loc*256+l)*1024 + p*32 + q]
#pragma unroll
    for (int mt = 0; mt < 4; ++mt) {
        const int mrow = (blockIdx.y << 7) + m_w + mt * 16;
        const int i_loc = mrow >> 5;
        const int p0 = (mrow & 31) + kg * 4;
#pragma unroll
        for (int nt = 0; nt < 4; ++nt) {
            const int ncol = (blockIdx.x << 7) + n_w + nt * 16;
            const int l = ncol >> 5;
            const int q = (ncol & 31) + lo;
            __hip_bfloat16* dst = (__hip_bfloat16*)&Pc[(((i_loc << 8) + l) << 10) + q];
#pragma unroll
            for (int r = 0; r < 4; ++r)
                dst[(p0 + r) << 5] = __float2bfloat16(acc[mt][nt][r] * sc);
        }
    }
}

// ------------- projection GEMM: out[pix][o] = rstd*(P[pix,:].G2[:,o] - mu*S1[o]) + S2[o]
// grid (256, 2): x = pix-block (64 rows of 16384 chunk), y = o-half (64).
// 256 thr = 4 waves, wave quadrant 32x32.
__global__ __launch_bounds__(256) void k_proj(
    const ushort* __restrict__ Pc, const ushort* __restrict__ G2swz,
    const float* __restrict__ muArr, const float* __restrict__ rstdArr,
    const float* __restrict__ S1, const float* __restrict__ S2,
    float* __restrict__ pair2, int ib)
{
    const int tid = threadIdx.x;
    const int w = tid >> 6, lane = tid & 63;
    const int m_w = (w >> 1) << 5;
    const int n_w = (w & 1) << 5;
    const int lo = lane & 15, kg = lane >> 4;
    const int row0 = (blockIdx.x << 6) + m_w;
    const int ntg0 = (blockIdx.y << 2) + (n_w >> 4);

    f32x4 acc[2][2] = {};
#pragma unroll 4
    for (int ks = 0; ks < 32; ++ks) {
        bf16x8 a[2], b[2];
#pragma unroll
        for (int mt = 0; mt < 2; ++mt)
            a[mt] = *(const bf16x8*)&Pc[(row0 + mt * 16 + lo) * 1024 + ks * 32 + kg * 8];
#pragma unroll
        for (int nt = 0; nt < 2; ++nt)
            b[nt] = *(const bf16x8*)&G2swz[((ks * 8 + ntg0 + nt) * 64 + lane) * 8];
#pragma unroll
        for (int mt = 0; mt < 2; ++mt)
#pragma unroll
            for (int nt = 0; nt < 2; ++nt)
                acc[mt][nt] = __builtin_amdgcn_mfma_f32_16x16x32_bf16(a[mt], b[nt], acc[mt][nt], 0, 0, 0);
    }
#pragma unroll
    for (int mt = 0; mt < 2; ++mt) {
#pragma unroll
        for (int r = 0; r < 4; ++r) {
            const int pix_loc = row0 + mt * 16 + kg * 4 + r;
            const int pixg = (ib << 8) + pix_loc;
            const float mu = muArr[pixg], rs = rstdArr[pixg];
#pragma unroll
            for (int nt = 0; nt < 2; ++nt) {
                const int o = (blockIdx.y << 6) + n_w + nt * 16 + lo;
                pair2[pixg * 128 + o] = rs * (acc[mt][nt][r] - mu * S1[o]) + S2[o];
            }
        }
    }
}

// ------------- 1x1 conv over concat(pair_orig, pair2) + Ai + Bl, + stats
__global__ __launch_bounds__(256) void k_conv1x1(
    const float* __restrict__ pairo, const float* __restrict__ pair2,
    const float* __restrict__ Ai, const float* __restrict__ Bl,
    const float* __restrict__ WcT, float* __restrict__ X0,
    float* __restrict__ ps, float* __restrict__ pq)
{
    __shared__ float cat_s[16 * 260];
    __shared__ float w_s[32 * 132];
    __shared__ float red_s[4][32][4], red_q[4][32][4];
    const int tid = threadIdx.x;
    const int pix0 = blockIdx.x << 4;
    for (int t = tid; t < 2048; t += 256) {
        const int px = t >> 7, c = t & 127;
        cat_s[px * 260 + c]       = pairo[(pix0 + px) * 128 + c];
        cat_s[px * 260 + 128 + c] = pair2[(pix0 + px) * 128 + c];
    }
    const int og = tid & 31, pg = tid >> 5;
    const int o0 = og << 2;
    float acc0[4] = {0.f, 0.f, 0.f, 0.f}, acc1[4] = {0.f, 0.f, 0.f, 0.f};
    for (int ch = 0; ch < 8; ++ch) {
        __syncthreads();
        for (int t = tid; t < 4096; t += 256) {
            const int o = t & 127, cc = t >> 7;
            w_s[cc * 132 + o] = WcT[(((ch << 5) + cc) << 7) + o];
        }
        __syncthreads();
        const int cb = ch << 5;
#pragma unroll 4
        for (int cc = 0; cc < 32; ++cc) {
            const float4 w4 = *(const float4*)&w_s[cc * 132 + o0];
            const float p0v = cat_s[(pg << 1) * 260 + cb + cc];
            const float p1v = cat_s[((pg << 1) + 1) * 260 + cb + cc];
            acc0[0] += p0v * w4.x; acc0[1] += p0v * w4.y; acc0[2] += p0v * w4.z; acc0[3] += p0v * w4.w;
            acc1[0] += p1v * w4.x; acc1[1] += p1v * w4.y; acc1[2] += p1v * w4.z; acc1[3] += p1v * w4.w;
        }
    }
    float v0[4], v1[4];
    {
        const int pix = pix0 + (pg << 1);
        const int ii = pix >> 8, ll = pix & 255;
        const float4 a4 = *(const float4*)&Ai[ii * 128 + o0];
        const float4 b4 = *(const float4*)&Bl[ll * 128 + o0];
        v0[0] = acc0[0] + a4.x + b4.x; v0[1] = acc0[1] + a4.y + b4.y;
        v0[2] = acc0[2] + a4.z + b4.z; v0[3] = acc0[3] + a4.w + b4.w;
        *(float4*)&X0[pix * 128 + o0] = make_float4(v0[0], v0[1], v0[2], v0[3]);
    }
    {
        const int pix = pix0 + (pg << 1) + 1;
        const int ii = pix >> 8, ll = pix & 255;
        const float4 a4 = *(const float4*)&Ai[ii * 128 + o0];
        const float4 b4 = *(const float4*)&Bl[ll * 128 + o0];
        v1[0] = acc1[0] + a4.x + b4.x; v1[1] = acc1[1] + a4.y + b4.y;
        v1[2] = acc1[2] + a4.z + b4.z; v1[3] = acc1[3] + a4.w + b4.w;
        *(float4*)&X0[pix * 128 + o0] = make_float4(v1[0], v1[1], v1[2], v1[3]);
    }
    float lsum[4], lsq[4];
#pragma unroll
    for (int b = 0; b < 4; ++b) {
        lsum[b] = v0[b] + v1[b];
        lsq[b] = v0[b] * v0[b] + v1[b] * v1[b];
    }
    const int wid = tid >> 6;
#pragma unroll
    for (int b = 0; b < 4; ++b) {
        lsum[b] += __shfl_xor(lsum[b], 32);
        lsq[b]  += __shfl_xor(lsq[b], 32);
    }
    if ((tid & 63) < 32) {
#pragma unroll
        for (int b = 0; b < 4; ++b) { red_s[wid][og][b] = lsum[b]; red_q[wid][og][b] = lsq[b]; }
    }
    __syncthreads();
    if (tid < 128) {
        const int o = tid, ogg = o >> 2, b = o & 3;
        const float s = red_s[0][ogg][b] + red_s[1][ogg][b] + red_s[2][ogg][b] + red_s[3][ogg][b];
        const float q = red_q[0][ogg][b] + red_q[1][ogg][b] + red_q[2][ogg][b] + red_q[3][ogg][b];
        ps[blockIdx.x * 128 + o] = s;
        pq[blockIdx.x * 128 + o] = q;
    }
}

// ------------------------------------------- per-channel IN params
__global__ __launch_bounds__(256) void k_stats(
    const float* __restrict__ ps, const float* __restrict__ pq, int R,
    const float* __restrict__ g, const float* __restrict__ be,
    float* __restrict__ scl, float* __restrict__ sft)
{
    const int o = blockIdx.x, tid = threadIdx.x;
    float s = 0.f, q = 0.f;
    for (int r = tid; r < R; r += 256) { s += ps[r * 128 + o]; q += pq[r * 128 + o]; }
#pragma unroll
    for (int off = 32; off; off >>= 1) { s += __shfl_down(s, off); q += __shfl_down(q, off); }
    __shared__ float rs[4], rq[4];
    if ((tid & 63) == 0) { rs[tid >> 6] = s; rq[tid >> 6] = q; }
    __syncthreads();
    if (tid == 0) {
        s = rs[0] + rs[1] + rs[2] + rs[3];
        q = rq[0] + rq[1] + rq[2] + rq[3];
        const float mean = s * (1.f / 65536.f);
        const float var = q * (1.f / 65536.f) - mean * mean;
        const float rstd = rsqrtf(var + 1e-6f);
        const float sc = g[o] * rstd;
        scl[o] = sc;
        sft[o] = be[o] - mean * sc;
    }
}

// ------------------------------------------- elementwise norm + ELU
__global__ __launch_bounds__(256) void k_norm_elu(
    const float* in, float* out,
    const float* __restrict__ scl, const float* __restrict__ sft)
{
    const int total = 2097152;
    for (int i = blockIdx.x * 256 + threadIdx.x; i < total; i += gridDim.x * 256) {
        const float4 v = ((const float4*)in)[i];
        const int o0 = (i & 31) << 2;
        const float4 sc = *(const float4*)&scl[o0];
        const float4 sh = *(const float4*)&sft[o0];
        float4 r;
        r.x = eluf(v.x * sc.x + sh.x);
        r.y = eluf(v.y * sc.y + sh.y);
        r.z = eluf(v.z * sc.z + sh.z);
        r.w = eluf(v.w * sc.w + sh.w);
        ((float4*)out)[i] = r;
    }
}

// ------------------------------------------- weight transpose [o][ic][ky][kx] -> [tap][ic][o]
__global__ __launch_bounds__(256) void k_wtrans(
    const float* __restrict__ src, float* __restrict__ dst)
{
    const int t = blockIdx.x * 256 + threadIdx.x;   // 147456
    const int kx = t % 3;
    const int t2 = t / 3;
    const int ky = t2 % 3;
    const int t3 = t2 / 3;
    const int ic = t3 & 127;
    const int o = t3 >> 7;
    dst[(((ky * 3 + kx) << 7) + ic) * 128 + o] = src[t];
}

// ------------------------------------------- 3x3 conv + block stats
__global__ __launch_bounds__(256) void k_conv3x3(
    const float* __restrict__ in, const float* __restrict__ wgtT,
    float* __restrict__ out, float* __restrict__ ps, float* __restrict__ pq)
{
    __shared__ float in_s[3 * 66 * 9];
    __shared__ float w_s[72 * 132];
    __shared__ float red_s[4][16][8], red_q[4][16][8];
    const int tid = threadIdx.x;
    const int x0 = blockIdx.x << 6;
    const int y = blockIdx.y;
    const int og = tid & 15, pg = tid >> 4;
    const int px0 = pg << 2;
    float acc[4][8];
#pragma unroll
    for (int a = 0; a < 4; ++a)
#pragma unroll
        for (int b = 0; b < 8; ++b) acc[a][b] = 0.f;

    for (int icc = 0; icc < 16; ++icc) {
        __syncthreads();
        for (int t = tid; t < 1584; t += 256) {
            const int ic = t & 7, cr = t >> 3;
            const int xl = cr % 66, ky = cr / 66;
            const int yy = y + ky - 1, xx = x0 + xl - 1;
            float v = 0.f;
            if ((unsigned)yy < 256u && (unsigned)xx < 256u)
                v = in[(((yy << 8) + xx) << 7) + (icc << 3) + ic];
            in_s[(ky * 66 + xl) * 9 + ic] = v;
        }
        for (int t = tid; t < 9216; t += 256) {
            const int o = t & 127, r = t >> 7;
            const int tap = r >> 3, icl = r & 7;
            w_s[r * 132 + o] = wgtT[(((tap << 7) + (icc << 3) + icl) << 7) + o];
        }
        __syncthreads();
#pragma unroll 1
        for (int tap = 0; tap < 9; ++tap) {
            const int ky = tap / 3, kx = tap % 3;
            const int ibase = (ky * 66 + px0 + kx) * 9;
#pragma unroll
            for (int icl = 0; icl < 8; ++icl) {
                const int r = (tap << 3) + icl;
                const float4 wlo = *(const float4*)&w_s[r * 132 + (og << 2)];
                const float4 whi = *(const float4*)&w_s[r * 132 + 64 + (og << 2)];
#pragma unroll
                for (int p = 0; p < 4; ++p) {
                    const float iv = in_s[ibase + p * 9 + icl];
                    acc[p][0] += iv * wlo.x; acc[p][1] += iv * wlo.y;
                    acc[p][2] += iv * wlo.z; acc[p][3] += iv * wlo.w;
                    acc[p][4] += iv * whi.x; acc[p][5] += iv * whi.y;
                    acc[p][6] += iv * whi.z; acc[p][7] += iv * whi.w;
                }
            }
        }
    }
    float lsum[8], lsq[8];
#pragma unroll
    for (int b = 0; b < 8; ++b) { lsum[b] = 0.f; lsq[b] = 0.f; }
#pragma unroll
    for (int p = 0; p < 4; ++p) {
        const int xx = x0 + px0 + p;
        const int base = (((y << 8) + xx) << 7);
        *(float4*)&out[base + (og << 2)] = make_float4(acc[p][0], acc[p][1], acc[p][2], acc[p][3]);
        *(float4*)&out[base + 64 + (og << 2)] = make_float4(acc[p][4], acc[p][5], acc[p][6], acc[p][7]);
#pragma unroll
        for (int b = 0; b < 8; ++b) { const float v = acc[p][b]; lsum[b] += v; lsq[b] += v * v; }
    }
#pragma unroll
    for (int b = 0; b < 8; ++b) {
        lsum[b] += __shfl_xor(lsum[b], 16); lsum[b] += __shfl_xor(lsum[b], 32);
        lsq[b]  += __shfl_xor(lsq[b], 16);  lsq[b]  += __shfl_xor(lsq[b], 32);
    }
    const int wid = tid >> 6;
    if ((tid & 63) < 16) {
#pragma unroll
        for (int b = 0; b < 8; ++b) { red_s[wid][og][b] = lsum[b]; red_q[wid][og][b] = lsq[b]; }
    }
    __syncthreads();
    if (tid < 128) {
        const int o = tid;
        int ogg, b;
        if (o < 64) { ogg = o >> 2; b = o & 3; } else { ogg = (o - 64) >> 2; b = 4 + ((o - 64) & 3); }
        const float s = red_s[0][ogg][b] + red_s[1][ogg][b] + red_s[2][ogg][b] + red_s[3][ogg][b];
        const float q = red_q[0][ogg][b] + red_q[1][ogg][b] + red_q[2][ogg][b] + red_q[3][ogg][b];
        const int blk = (y << 2) + blockIdx.x;
        ps[blk * 128 + o] = s;
        pq[blk * 128 + o] = q;
    }
}

// ------------------------------------------- final: out = elu(x1 + norm(h2))
__global__ __launch_bounds__(256) void k_final(
    const float* x1, const float* __restrict__ h,
    const float* __restrict__ scl, const float* __restrict__ sft,
    float* outp)
{
    const int total = 2097152;
    for (int i = blockIdx.x * 256 + threadIdx.x; i < total; i += gridDim.x * 256) {
        const float4 a = ((const float4*)x1)[i];
        const float4 hv = ((const float4*)h)[i];
        const int o0 = (i & 31) << 2;
        const float4 sc = *(const float4*)&scl[o0];
        const float4 sh = *(const float4*)&sft[o0];
        float4 r;
        r.x = eluf(a.x + hv.x * sc.x + sh.x);
        r.y = eluf(a.y + hv.y * sc.y + sh.y);
        r.z = eluf(a.z + hv.z * sc.z + sh.z);
        r.w = eluf(a.w + hv.w * sc.w + sh.w);
        ((float4*)outp)[i] = r;
    }
}

extern "C" void kernel_launch(void* const* d_in, const int* in_sizes, int n_in,
                              void* d_out, int out_size, void* d_ws, size_t ws_size,
                              hipStream_t stream)
{
    const float* msa   = (const float*)d_in[0];
    const float* pairo = (const float*)d_in[1];
    const float* W1    = (const float*)d_in[2];
    const float* b1    = (const float*)d_in[3];
    const float* g_ln  = (const float*)d_in[4];
    const float* be_ln = (const float*)d_in[5];
    const float* W2    = (const float*)d_in[6];
    const float* b2    = (const float*)d_in[7];
    const float* Wc0   = (const float*)d_in[8];
    const float* g0    = (const float*)d_in[9];
    const float* be0   = (const float*)d_in[10];
    const float* Wr1   = (const float*)d_in[11];
    const float* g1    = (const float*)d_in[12];
    const float* be1   = (const float*)d_in[13];
    const float* Wr2   = (const float*)d_in[14];
    const float* g2    = (const float*)d_in[15];
    const float* be2   = (const float*)d_in[16];

    float* ws = (float*)d_ws;
    ushort* xdT   = (ushort*)ws;                    // 524288 bf16 = 262144 f
    float* feat   = ws + 262144;                    // 32768
    float* Ai     = ws + 294912;                    // 32768
    float* Bl     = ws + 327680;                    // 32768
    float* S1     = ws + 360448;                    // 128
    float* S2     = ws + 360576;                    // 128
    float* scl    = ws + 360704;                    // 128
    float* sft    = ws + 360832;                    // 128
    float* WcT    = ws + 360960;                    // 32768
    ushort* G2swz = (ushort*)(ws + 393728);         // 131072 bf16 = 65536 f
    float* muArr  = ws + 459264;                    // 65536
    float* rstdA  = ws + 524800;                    // 65536
    float* ps     = ws + 590336;                    // 524288
    float* pq     = ws + 1114624;                   // 524288
    float* wgtT   = ws + 1638912;                   // 147456
    float* pair2  = ws + 1786368;                   // 8388608
    float* X0     = ws + 10174976;                  // 8388608 (also Pc: 16777216 bf16)
    ushort* Pc    = (ushort*)X0;
    float* X1     = (float*)d_out;

    k_xdown<<<dim3(2048), dim3(256), 0, stream>>>(msa, W1, b1, xdT);
    k_feat<<<dim3(128), dim3(256), 0, stream>>>(msa, feat);
    k_g2<<<dim3(128), dim3(256), 0, stream>>>(W2, g_ln, be_ln, b2, S1, S2);
    k_g2swz<<<dim3(512), dim3(256), 0, stream>>>(W2, g_ln, G2swz);
    k_wct<<<dim3(128), dim3(256), 0, stream>>>(Wc0, WcT);
    k_ab<<<dim3(256), dim3(128), 0, stream>>>(feat, Wc0, Ai, Bl);

    for (int c = 0; c < 4; ++c) {
        const int ib = c * 64;
        k_outer<<<dim3(64, 16), dim3(256), 0, stream>>>(xdT, Pc, muArr, rstdA, ib);
        k_proj<<<dim3(256, 2), dim3(256), 0, stream>>>(Pc, G2swz, muArr, rstdA, S1, S2, pair2, ib);
    }

    k_conv1x1<<<dim3(4096), dim3(256), 0, stream>>>(pairo, pair2, Ai, Bl, WcT, X0, ps, pq);
    k_stats<<<dim3(128), dim3(256), 0, stream>>>(ps, pq, 4096, g0, be0, scl, sft);
    k_norm_elu<<<dim3(4096), dim3(256), 0, stream>>>(X0, X1, scl, sft);

    k_wtrans<<<dim3(576), dim3(256), 0, stream>>>(Wr1, wgtT);
    k_conv3x3<<<dim3(4, 256), dim3(256), 0, stream>>>(X1, wgtT, X0, ps, pq);
    k_stats<<<dim3(128), dim3(256), 0, stream>>>(ps, pq, 1024, g1, be1, scl, sft);
    k_norm_elu<<<dim3(4096), dim3(256), 0, stream>>>(X0, X0, scl, sft);

    k_wtrans<<<dim3(576), dim3(256), 0, stream>>>(Wr2, wgtT);
    k_conv3x3<<<dim3(4, 256), dim3(256), 0, stream>>>(X0, wgtT, pair2, ps, pq);
    k_stats<<<dim3(128), dim3(256), 0, stream>>>(ps, pq, 1024, g2, be2, scl, sft);

    k_final<<<dim3(4096), dim3(256), 0, stream>>>(X1, pair2, scl, sft, (float*)d_out);
}

// Round 3
// 383.938 us; speedup vs baseline: 4.0936x; 2.6565x over previous
//
#include <hip/hip_runtime.h>
#include <hip/hip_bf16.h>
#include <math.h>

// Shapes: B=1, N=64, L=256, nf=64, npj=32, nfo=128
// pair path + all convs: bf16 MFMA (16x16x32).
// Fragment conventions (validated in rounds 1-2):
//   A-frag: row = lane&15, k = (lane>>4)*8 + j   (8 bf16 per lane, contiguous)
//   B-frag: col = lane&15, k = (lane>>4)*8 + j
//   C-frag: col = lane&15, row = (lane>>4)*4 + r

typedef __attribute__((ext_vector_type(8))) short bf16x8;
typedef __attribute__((ext_vector_type(4))) float f32x4;

__device__ __forceinline__ float eluf(float x) { return x > 0.f ? x : expm1f(x); }
__device__ __forceinline__ ushort f2b(float f) {
    unsigned u = __float_as_uint(f);
    return (ushort)((u + 0x7fff + ((u >> 16) & 1)) >> 16);
}

// ---------------------------------------------------------------- x_down -> xdT bf16
__global__ __launch_bounds__(256) void k_xdown(
    const float* __restrict__ msa, const float* __restrict__ W1,
    const float* __restrict__ b1, ushort* __restrict__ xdT)
{
    __shared__ float w1s[32 * 65];
    const int tid = threadIdx.x;
    for (int t = tid; t < 2048; t += 256) w1s[(t >> 6) * 65 + (t & 63)] = W1[t];
    __syncthreads();
    const int id = blockIdx.x * 256 + tid;
    const int p = id & 31, l = (id >> 5) & 255, n = id >> 13;
    const float* mrow = msa + (((n << 8) + l) << 6);
    const float* wrow = w1s + p * 65;
    float s = 0.f;
#pragma unroll 8
    for (int f = 0; f < 64; ++f) s += mrow[f] * wrow[f];
    xdT[(((l << 5) + p) << 6) + n] = f2b(s + b1[p]);
}

// ---------------------------------------------------------------- feat_1d
__global__ __launch_bounds__(256) void k_feat(
    const float* __restrict__ msa, float* __restrict__ feat)
{
    const int id = blockIdx.x * 256 + threadIdx.x;   // 32768
    const int c = id & 127, l = id >> 7;
    float v;
    if (c < 64) {
        float s = 0.f;
        for (int n = 0; n < 64; ++n) s += msa[(((n << 8) + l) << 6) + c];
        v = s * (1.f / 64.f);
    } else {
        v = msa[(l << 6) + (c - 64)];
    }
    feat[id] = v;
}

// ------------------------------------------- S1[o]=sum_c g*W2, S2[o]=sum_c be*W2 + b2
__global__ __launch_bounds__(256) void k_g2(
    const float* __restrict__ W2, const float* __restrict__ g_ln,
    const float* __restrict__ be_ln, const float* __restrict__ b2,
    float* __restrict__ S1, float* __restrict__ S2)
{
    const int o = blockIdx.x, tid = threadIdx.x;
    float s1 = 0.f, s2 = 0.f;
    for (int c = tid; c < 1024; c += 256) {
        float w = W2[o * 1024 + c];
        s1 += g_ln[c] * w;
        s2 += be_ln[c] * w;
    }
#pragma unroll
    for (int off = 32; off; off >>= 1) { s1 += __shfl_down(s1, off); s2 += __shfl_down(s2, off); }
    __shared__ float r1[4], r2[4];
    if ((tid & 63) == 0) { r1[tid >> 6] = s1; r2[tid >> 6] = s2; }
    __syncthreads();
    if (tid == 0) {
        S1[o] = r1[0] + r1[1] + r1[2] + r1[3];
        S2[o] = r2[0] + r2[1] + r2[2] + r2[3] + b2[o];
    }
}

// ------------------------------------------- G2 in B-fragment bf16 layout
__global__ __launch_bounds__(256) void k_g2swz(
    const float* __restrict__ W2, const float* __restrict__ g_ln,
    ushort* __restrict__ G2swz)
{
    const int idx = blockIdx.x * 256 + threadIdx.x;   // 131072
    const int j = idx & 7, lane = (idx >> 3) & 63, nt = (idx >> 9) & 7, kt = idx >> 12;
    const int k = kt * 32 + (lane >> 4) * 8 + j;
    const int o = nt * 16 + (lane & 15);
    G2swz[idx] = f2b(g_ln[k] * W2[o * 1024 + k]);
}

// ------------------------------------------- Wc0[:, 0:256] in B-frag bf16 layout
__global__ __launch_bounds__(256) void k_wcswz(
    const float* __restrict__ Wc0, ushort* __restrict__ WCB)
{
    const int idx = blockIdx.x * 256 + threadIdx.x;   // 32768
    const int j = idx & 7, lane = (idx >> 3) & 63, nt = (idx >> 9) & 7, ks = idx >> 12;
    const int ic = ks * 32 + (lane >> 4) * 8 + j;
    const int o = nt * 16 + (lane & 15);
    WCB[idx] = f2b(Wc0[o * 512 + ic]);
}

// ------------------------------------------- 3x3 weights [o][ic][ky][kx] -> B-frag bf16
__global__ __launch_bounds__(256) void k_wswz(
    const float* __restrict__ Wr, ushort* __restrict__ WB)
{
    const int idx = blockIdx.x * 256 + threadIdx.x;   // 147456
    const int j = idx & 7, lane = (idx >> 3) & 63, nt = (idx >> 9) & 7;
    const int ks = (idx >> 12) & 3, tap = idx >> 14;
    const int ic = ks * 32 + (lane >> 4) * 8 + j;
    const int o = nt * 16 + (lane & 15);
    WB[idx] = f2b(Wr[o * 1152 + ic * 9 + tap]);
}

// ------------------------------------------- fp32 -> bf16 bulk convert
__global__ __launch_bounds__(256) void k_cvt(
    const float* __restrict__ src, ushort* __restrict__ dst)
{
    const int i = blockIdx.x * 256 + threadIdx.x;   // 2097152
    const float4 v = ((const float4*)src)[i];
    ushort4 pk;
    pk.x = f2b(v.x); pk.y = f2b(v.y); pk.z = f2b(v.z); pk.w = f2b(v.w);
    ((ushort4*)dst)[i] = pk;
}

// ------------------------------------------- Ai/Bl from feat & Wc0 tails
__global__ __launch_bounds__(128) void k_ab(
    const float* __restrict__ feat, const float* __restrict__ Wc0,
    float* __restrict__ Ai, float* __restrict__ Bl)
{
    __shared__ float fs[128];
    const int r = blockIdx.x, o = threadIdx.x;
    fs[o] = feat[r * 128 + o];
    __syncthreads();
    const float* wa = Wc0 + o * 512 + 256;
    const float* wb = Wc0 + o * 512 + 384;
    float a = 0.f, b = 0.f;
#pragma unroll 4
    for (int c = 0; c < 128; ++c) { float f = fs[c]; a += f * wa[c]; b += f * wb[c]; }
    Ai[r * 128 + o] = a;
    Bl[r * 128 + o] = b;
}

// ------------- outer-product GEMM + per-(i,l) LN stats
__global__ __launch_bounds__(256) void k_outer(
    const ushort* __restrict__ xdT, ushort* __restrict__ Pc,
    float* __restrict__ muArr, float* __restrict__ rstdArr, int ib)
{
    const int tid = threadIdx.x;
    const int w = tid >> 6, lane = tid & 63;
    const int m_w = (w >> 1) << 6;
    const int n_w = (w & 1) << 6;
    const int lo = lane & 15, kg = lane >> 4;
    const int rowA0 = (ib << 5) + (blockIdx.y << 7) + m_w;
    const int rowB0 = (blockIdx.x << 7) + n_w;

    f32x4 acc[4][4] = {};
#pragma unroll
    for (int ks = 0; ks < 2; ++ks) {
        bf16x8 a[4], b[4];
#pragma unroll
        for (int mt = 0; mt < 4; ++mt)
            a[mt] = *(const bf16x8*)&xdT[(rowA0 + mt * 16 + lo) * 64 + ks * 32 + kg * 8];
#pragma unroll
        for (int nt = 0; nt < 4; ++nt)
            b[nt] = *(const bf16x8*)&xdT[(rowB0 + nt * 16 + lo) * 64 + ks * 32 + kg * 8];
#pragma unroll
        for (int mt = 0; mt < 4; ++mt)
#pragma unroll
            for (int nt = 0; nt < 4; ++nt)
                acc[mt][nt] = __builtin_amdgcn_mfma_f32_16x16x32_bf16(a[mt], b[nt], acc[mt][nt], 0, 0, 0);
    }

    const float sc = 1.f / 64.f;
#pragma unroll
    for (int ii = 0; ii < 2; ++ii) {
#pragma unroll
        for (int ll = 0; ll < 2; ++ll) {
            float s = 0.f, q = 0.f;
#pragma unroll
            for (int dm = 0; dm < 2; ++dm)
#pragma unroll
                for (int dn = 0; dn < 2; ++dn)
#pragma unroll
                    for (int r = 0; r < 4; ++r) {
                        const float v = acc[ii * 2 + dm][ll * 2 + dn][r] * sc;
                        s += v; q += v * v;
                    }
#pragma unroll
            for (int off = 1; off < 64; off <<= 1) { s += __shfl_xor(s, off); q += __shfl_xor(q, off); }
            if (lane == 0) {
                const int i_loc = (((blockIdx.y << 7) + m_w) >> 5) + ii;
                const int l = (((blockIdx.x << 7) + n_w) >> 5) + ll;
                const int pixg = ((ib + i_loc) << 8) + l;
                const float mu = s * (1.f / 1024.f);
                const float var = q * (1.f / 1024.f) - mu * mu;
                muArr[pixg] = mu;
                rstdArr[pixg] = rsqrtf(var + 1e-5f);
            }
        }
    }
#pragma unroll
    for (int mt = 0; mt < 4; ++mt) {
        const int mrow = (blockIdx.y << 7) + m_w + mt * 16;
        const int i_loc = mrow >> 5;
        const int p0 = (mrow & 31) + kg * 4;
#pragma unroll
        for (int nt = 0; nt < 4; ++nt) {
            const int ncol = (blockIdx.x << 7) + n_w + nt * 16;
            const int l = ncol >> 5;
            const int q = (ncol & 31) + lo;
            ushort* dst = &Pc[(((i_loc << 8) + l) << 10) + q];
#pragma unroll
            for (int r = 0; r < 4; ++r)
                dst[(p0 + r) << 5] = f2b(acc[mt][nt][r] * sc);
        }
    }
}

// ------------- projection GEMM, LN folded; writes pair2 bf16
__global__ __launch_bounds__(256) void k_proj(
    const ushort* __restrict__ Pc, const ushort* __restrict__ G2swz,
    const float* __restrict__ muArr, const float* __restrict__ rstdArr,
    const float* __restrict__ S1, const float* __restrict__ S2,
    ushort* __restrict__ pair2b, int ib)
{
    const int tid = threadIdx.x;
    const int w = tid >> 6, lane = tid & 63;
    const int m_w = (w >> 1) << 5;
    const int n_w = (w & 1) << 5;
    const int lo = lane & 15, kg = lane >> 4;
    const int row0 = (blockIdx.x << 6) + m_w;
    const int ntg0 = (blockIdx.y << 2) + (n_w >> 4);

    f32x4 acc[2][2] = {};
#pragma unroll 4
    for (int ks = 0; ks < 32; ++ks) {
        bf16x8 a[2], b[2];
#pragma unroll
        for (int mt = 0; mt < 2; ++mt)
            a[mt] = *(const bf16x8*)&Pc[(row0 + mt * 16 + lo) * 1024 + ks * 32 + kg * 8];
#pragma unroll
        for (int nt = 0; nt < 2; ++nt)
            b[nt] = *(const bf16x8*)&G2swz[((ks * 8 + ntg0 + nt) * 64 + lane) * 8];
#pragma unroll
        for (int mt = 0; mt < 2; ++mt)
#pragma unroll
            for (int nt = 0; nt < 2; ++nt)
                acc[mt][nt] = __builtin_amdgcn_mfma_f32_16x16x32_bf16(a[mt], b[nt], acc[mt][nt], 0, 0, 0);
    }
#pragma unroll
    for (int mt = 0; mt < 2; ++mt) {
#pragma unroll
        for (int r = 0; r < 4; ++r) {
            const int pix_loc = row0 + mt * 16 + kg * 4 + r;
            const int pixg = (ib << 8) + pix_loc;
            const float mu = muArr[pixg], rs = rstdArr[pixg];
#pragma unroll
            for (int nt = 0; nt < 2; ++nt) {
                const int o = (blockIdx.y << 6) + n_w + nt * 16 + lo;
                pair2b[pixg * 128 + o] = f2b(rs * (acc[mt][nt][r] - mu * S1[o]) + S2[o]);
            }
        }
    }
}

// ------------- 1x1 conv (MFMA): cat(pairoB, pair2B) @ WCB + Ai + Bl, + IN partials
// grid 1024: 64 px/block. 4 waves: m_w=(w>>1)*32 px, n_w=(w&1)*64 o.
__global__ __launch_bounds__(256) void k_conv1x1m(
    const ushort* __restrict__ pairoB, const ushort* __restrict__ pair2B,
    const float* __restrict__ Ai, const float* __restrict__ Bl,
    const ushort* __restrict__ WCB, float* __restrict__ X0,
    float* __restrict__ ps, float* __restrict__ pq)
{
    const int tid = threadIdx.x;
    const int w = tid >> 6, lane = tid & 63;
    const int lo = lane & 15, kg = lane >> 4;
    const int m_w = (w >> 1) << 5;
    const int n_w = (w & 1) << 6;
    const int n4 = (w & 1) << 2;
    const int px0 = blockIdx.x << 6;
    const int iu = px0 >> 8;

    f32x4 acc[2][4] = {};
#pragma unroll
    for (int ks = 0; ks < 8; ++ks) {
        const ushort* src = (ks < 4) ? pairoB : pair2B;
        const int coff = (ks & 3) * 32 + kg * 8;
        bf16x8 a[2], b[4];
#pragma unroll
        for (int mt = 0; mt < 2; ++mt)
            a[mt] = *(const bf16x8*)&src[(px0 + m_w + mt * 16 + lo) * 128 + coff];
#pragma unroll
        for (int nt = 0; nt < 4; ++nt)
            b[nt] = *(const bf16x8*)&WCB[((ks * 8 + n4 + nt) * 64 + lane) * 8];
#pragma unroll
        for (int mt = 0; mt < 2; ++mt)
#pragma unroll
            for (int nt = 0; nt < 4; ++nt)
                acc[mt][nt] = __builtin_amdgcn_mfma_f32_16x16x32_bf16(a[mt], b[nt], acc[mt][nt], 0, 0, 0);
    }

    float lsum[4] = {0.f, 0.f, 0.f, 0.f}, lsq[4] = {0.f, 0.f, 0.f, 0.f};
#pragma unroll
    for (int nt = 0; nt < 4; ++nt) {
        const int o = n_w + nt * 16 + lo;
        const float aadd = Ai[iu * 128 + o];
#pragma unroll
        for (int mt = 0; mt < 2; ++mt) {
#pragma unroll
            for (int r = 0; r < 4; ++r) {
                const int lpos = (px0 & 255) + m_w + mt * 16 + kg * 4 + r;
                const float v = acc[mt][nt][r] + aadd + Bl[lpos * 128 + o];
                X0[((px0 + m_w + mt * 16 + kg * 4 + r) << 7) + o] = v;
                lsum[nt] += v; lsq[nt] += v * v;
            }
        }
    }
#pragma unroll
    for (int nt = 0; nt < 4; ++nt) {
        lsum[nt] += __shfl_xor(lsum[nt], 16); lsum[nt] += __shfl_xor(lsum[nt], 32);
        lsq[nt]  += __shfl_xor(lsq[nt], 16);  lsq[nt]  += __shfl_xor(lsq[nt], 32);
    }
    __shared__ float red_s[4][4][16], red_q[4][4][16];
    if (kg == 0) {
#pragma unroll
        for (int nt = 0; nt < 4; ++nt) { red_s[w][nt][lo] = lsum[nt]; red_q[w][nt][lo] = lsq[nt]; }
    }
    __syncthreads();
    if (tid < 128) {
        const int o = tid;
        const int half = o >> 6, nt = (o & 63) >> 4, lo2 = o & 15;
        const float s = red_s[half][nt][lo2] + red_s[half + 2][nt][lo2];
        const float q = red_q[half][nt][lo2] + red_q[half + 2][nt][lo2];
        ps[blockIdx.x * 128 + o] = s;
        pq[blockIdx.x * 128 + o] = q;
    }
}

// ------------- 3x3 conv (MFMA implicit im2col), + IN partials. No LDS for data.
// grid (4,256): x0=bx*64, y=by. 4 waves: m_w=(w>>1)*32 px, n_w=(w&1)*64 o.
__global__ __launch_bounds__(256) void k_conv3x3m(
    const ushort* __restrict__ Xb, const ushort* __restrict__ WB,
    float* __restrict__ out, float* __restrict__ ps, float* __restrict__ pq)
{
    const int tid = threadIdx.x;
    const int w = tid >> 6, lane = tid & 63;
    const int lo = lane & 15, kg = lane >> 4;
    const int m_w = (w >> 1) << 5;
    const int n_w = (w & 1) << 6;
    const int n4 = (w & 1) << 2;
    const int x0 = blockIdx.x << 6;
    const int y = blockIdx.y;
    const bf16x8 ZB = {};

    f32x4 acc[2][4] = {};
    for (int tap = 0; tap < 9; ++tap) {
        const int ky = tap / 3, kx = tap % 3;
        const int yy = y + ky - 1;
        if ((unsigned)yy >= 256u) continue;
        const int rowbase = yy << 8;
        int abase[2]; bool ok[2];
#pragma unroll
        for (int mt = 0; mt < 2; ++mt) {
            const int xx = x0 + m_w + mt * 16 + lo + kx - 1;
            const int xc = xx < 0 ? 0 : (xx > 255 ? 255 : xx);
            ok[mt] = ((unsigned)xx < 256u);
            abase[mt] = ((rowbase + xc) << 7) + kg * 8;
        }
#pragma unroll
        for (int ks = 0; ks < 4; ++ks) {
            bf16x8 a[2], b[4];
#pragma unroll
            for (int mt = 0; mt < 2; ++mt) {
                bf16x8 v = *(const bf16x8*)&Xb[abase[mt] + ks * 32];
                a[mt] = ok[mt] ? v : ZB;
            }
#pragma unroll
            for (int nt = 0; nt < 4; ++nt)
                b[nt] = *(const bf16x8*)&WB[(((tap * 4 + ks) * 8 + n4 + nt) * 64 + lane) * 8];
#pragma unroll
            for (int mt = 0; mt < 2; ++mt)
#pragma unroll
                for (int nt = 0; nt < 4; ++nt)
                    acc[mt][nt] = __builtin_amdgcn_mfma_f32_16x16x32_bf16(a[mt], b[nt], acc[mt][nt], 0, 0, 0);
        }
    }

    float lsum[4] = {0.f, 0.f, 0.f, 0.f}, lsq[4] = {0.f, 0.f, 0.f, 0.f};
#pragma unroll
    for (int nt = 0; nt < 4; ++nt) {
        const int o = n_w + nt * 16 + lo;
#pragma unroll
        for (int mt = 0; mt < 2; ++mt) {
#pragma unroll
            for (int r = 0; r < 4; ++r) {
                const int xo = x0 + m_w + mt * 16 + kg * 4 + r;
                const float v = acc[mt][nt][r];
                out[(((y << 8) + xo) << 7) + o] = v;
                lsum[nt] += v; lsq[nt] += v * v;
            }
        }
    }
#pragma unroll
    for (int nt = 0; nt < 4; ++nt) {
        lsum[nt] += __shfl_xor(lsum[nt], 16); lsum[nt] += __shfl_xor(lsum[nt], 32);
        lsq[nt]  += __shfl_xor(lsq[nt], 16);  lsq[nt]  += __shfl_xor(lsq[nt], 32);
    }
    __shared__ float red_s[4][4][16], red_q[4][4][16];
    if (kg == 0) {
#pragma unroll
        for (int nt = 0; nt < 4; ++nt) { red_s[w][nt][lo] = lsum[nt]; red_q[w][nt][lo] = lsq[nt]; }
    }
    __syncthreads();
    if (tid < 128) {
        const int o = tid;
        const int half = o >> 6, nt = (o & 63) >> 4, lo2 = o & 15;
        const float s = red_s[half][nt][lo2] + red_s[half + 2][nt][lo2];
        const float q = red_q[half][nt][lo2] + red_q[half + 2][nt][lo2];
        const int blk = (y << 2) + blockIdx.x;
        ps[blk * 128 + o] = s;
        pq[blk * 128 + o] = q;
    }
}

// ------------------------------------------- per-channel IN params
__global__ __launch_bounds__(256) void k_stats(
    const float* __restrict__ ps, const float* __restrict__ pq, int R,
    const float* __restrict__ g, const float* __restrict__ be,
    float* __restrict__ scl, float* __restrict__ sft)
{
    const int o = blockIdx.x, tid = threadIdx.x;
    float s = 0.f, q = 0.f;
    for (int r = tid; r < R; r += 256) { s += ps[r * 128 + o]; q += pq[r * 128 + o]; }
#pragma unroll
    for (int off = 32; off; off >>= 1) { s += __shfl_down(s, off); q += __shfl_down(q, off); }
    __shared__ float rs[4], rq[4];
    if ((tid & 63) == 0) { rs[tid >> 6] = s; rq[tid >> 6] = q; }
    __syncthreads();
    if (tid == 0) {
        s = rs[0] + rs[1] + rs[2] + rs[3];
        q = rq[0] + rq[1] + rq[2] + rq[3];
        const float mean = s * (1.f / 65536.f);
        const float var = q * (1.f / 65536.f) - mean * mean;
        const float rstd = rsqrtf(var + 1e-6f);
        const float sc = g[o] * rstd;
        scl[o] = sc;
        sft[o] = be[o] - mean * sc;
    }
}

// ------------------------------------------- norm + ELU; fp32 out optional + bf16 out
__global__ __launch_bounds__(256) void k_norm_elu(
    const float* in, float* outf, ushort* outb,
    const float* __restrict__ scl, const float* __restrict__ sft)
{
    const int total = 2097152;
    for (int i = blockIdx.x * 256 + threadIdx.x; i < total; i += gridDim.x * 256) {
        const float4 v = ((const float4*)in)[i];
        const int o0 = (i & 31) << 2;
        const float4 sc = *(const float4*)&scl[o0];
        const float4 sh = *(const float4*)&sft[o0];
        float4 r;
        r.x = eluf(v.x * sc.x + sh.x);
        r.y = eluf(v.y * sc.y + sh.y);
        r.z = eluf(v.z * sc.z + sh.z);
        r.w = eluf(v.w * sc.w + sh.w);
        if (outf) ((float4*)outf)[i] = r;
        ushort4 pk;
        pk.x = f2b(r.x); pk.y = f2b(r.y); pk.z = f2b(r.z); pk.w = f2b(r.w);
        ((ushort4*)outb)[i] = pk;
    }
}

// ------------------------------------------- final: out = elu(x1 + norm(h2))
__global__ __launch_bounds__(256) void k_final(
    const float* x1, const float* __restrict__ h,
    const float* __restrict__ scl, const float* __restrict__ sft,
    float* outp)
{
    const int total = 2097152;
    for (int i = blockIdx.x * 256 + threadIdx.x; i < total; i += gridDim.x * 256) {
        const float4 a = ((const float4*)x1)[i];
        const float4 hv = ((const float4*)h)[i];
        const int o0 = (i & 31) << 2;
        const float4 sc = *(const float4*)&scl[o0];
        const float4 sh = *(const float4*)&sft[o0];
        float4 r;
        r.x = eluf(a.x + hv.x * sc.x + sh.x);
        r.y = eluf(a.y + hv.y * sc.y + sh.y);
        r.z = eluf(a.z + hv.z * sc.z + sh.z);
        r.w = eluf(a.w + hv.w * sc.w + sh.w);
        ((float4*)outp)[i] = r;
    }
}

extern "C" void kernel_launch(void* const* d_in, const int* in_sizes, int n_in,
                              void* d_out, int out_size, void* d_ws, size_t ws_size,
                              hipStream_t stream)
{
    const float* msa   = (const float*)d_in[0];
    const float* pairo = (const float*)d_in[1];
    const float* W1    = (const float*)d_in[2];
    const float* b1    = (const float*)d_in[3];
    const float* g_ln  = (const float*)d_in[4];
    const float* be_ln = (const float*)d_in[5];
    const float* W2    = (const float*)d_in[6];
    const float* b2    = (const float*)d_in[7];
    const float* Wc0   = (const float*)d_in[8];
    const float* g0    = (const float*)d_in[9];
    const float* be0   = (const float*)d_in[10];
    const float* Wr1   = (const float*)d_in[11];
    const float* g1    = (const float*)d_in[12];
    const float* be1   = (const float*)d_in[13];
    const float* Wr2   = (const float*)d_in[14];
    const float* g2    = (const float*)d_in[15];
    const float* be2   = (const float*)d_in[16];

    float* ws = (float*)d_ws;
    ushort* xdT   = (ushort*)ws;                    // 262144 f
    float* feat   = ws + 262144;                    // 32768
    float* Ai     = ws + 294912;                    // 32768
    float* Bl     = ws + 327680;                    // 32768
    float* S1     = ws + 360448;                    // 128
    float* S2     = ws + 360576;                    // 128
    float* scl    = ws + 360704;                    // 128
    float* sft    = ws + 360832;                    // 128
    ushort* WCB   = (ushort*)(ws + 360960);         // 16384 f (32768 bf16)
    ushort* G2swz = (ushort*)(ws + 393728);         // 65536 f
    float* muArr  = ws + 459264;                    // 65536
    float* rstdA  = ws + 524800;                    // 65536
    float* ps     = ws + 590336;                    // 524288
    float* pq     = ws + 1114624;                   // 524288
    ushort* WB1   = (ushort*)(ws + 1638912);        // 73728 f (147456 bf16)
    ushort* WB2   = (ushort*)(ws + 1712640);        // 73728 f
    float* R1     = ws + 1786368;                   // 8388608 f
    float* R2     = ws + 10174976;                  // 8388608 f
    // R1 aliases: pairoB [0,4.2M f) -> later X1b; pair2B [4.2M,8.4M f) -> later X2b
    ushort* pairoB = (ushort*)R1;
    ushort* pair2B = (ushort*)(R1 + 4194304);
    ushort* X1b    = (ushort*)R1;
    ushort* X2b    = (ushort*)(R1 + 4194304);
    // R2 aliases: Pc -> X0 -> H -> H2 (sequential lifetimes)
    ushort* Pc = (ushort*)R2;
    float* X0  = R2;
    float* H   = R2;
    float* H2  = R2;
    float* X1  = (float*)d_out;

    k_xdown<<<dim3(2048), dim3(256), 0, stream>>>(msa, W1, b1, xdT);
    k_feat<<<dim3(128), dim3(256), 0, stream>>>(msa, feat);
    k_g2<<<dim3(128), dim3(256), 0, stream>>>(W2, g_ln, be_ln, b2, S1, S2);
    k_g2swz<<<dim3(512), dim3(256), 0, stream>>>(W2, g_ln, G2swz);
    k_wcswz<<<dim3(128), dim3(256), 0, stream>>>(Wc0, WCB);
    k_ab<<<dim3(256), dim3(128), 0, stream>>>(feat, Wc0, Ai, Bl);
    k_cvt<<<dim3(8192), dim3(256), 0, stream>>>(pairo, pairoB);
    k_wswz<<<dim3(576), dim3(256), 0, stream>>>(Wr1, WB1);
    k_wswz<<<dim3(576), dim3(256), 0, stream>>>(Wr2, WB2);

    for (int c = 0; c < 4; ++c) {
        const int ib = c * 64;
        k_outer<<<dim3(64, 16), dim3(256), 0, stream>>>(xdT, Pc, muArr, rstdA, ib);
        k_proj<<<dim3(256, 2), dim3(256), 0, stream>>>(Pc, G2swz, muArr, rstdA, S1, S2, pair2B, ib);
    }

    k_conv1x1m<<<dim3(1024), dim3(256), 0, stream>>>(pairoB, pair2B, Ai, Bl, WCB, X0, ps, pq);
    k_stats<<<dim3(128), dim3(256), 0, stream>>>(ps, pq, 1024, g0, be0, scl, sft);
    k_norm_elu<<<dim3(4096), dim3(256), 0, stream>>>(X0, X1, X1b, scl, sft);

    k_conv3x3m<<<dim3(4, 256), dim3(256), 0, stream>>>(X1b, WB1, H, ps, pq);
    k_stats<<<dim3(128), dim3(256), 0, stream>>>(ps, pq, 1024, g1, be1, scl, sft);
    k_norm_elu<<<dim3(4096), dim3(256), 0, stream>>>(H, nullptr, X2b, scl, sft);

    k_conv3x3m<<<dim3(4, 256), dim3(256), 0, stream>>>(X2b, WB2, H2, ps, pq);
    k_stats<<<dim3(128), dim3(256), 0, stream>>>(ps, pq, 1024, g2, be2, scl, sft);

    k_final<<<dim3(4096), dim3(256), 0, stream>>>(X1, H2, scl, sft, (float*)d_out);
}